// Round 11
// baseline (54.935 us; speedup 1.0000x reference)
//
#include <hip/hip_runtime.h>

// Problem constants
#define BH      65536     // B*H
#define DSTATE  75
#define EMBD    256
#define NROWS   32        // rows per block; 4 rows per 32-lane group
#define NTHREADS 256
#define NBLOCKS (BH / NROWS)   // 2048

typedef _Float16 h2    __attribute__((ext_vector_type(2)));
typedef _Float16 f16x8 __attribute__((ext_vector_type(8)));
typedef float    f32x4 __attribute__((ext_vector_type(4)));

__device__ __forceinline__ h2 u2h(unsigned int u) {
    union { unsigned int u; h2 h; } c; c.u = u; return c.h;
}
__device__ __forceinline__ unsigned int h2u(h2 h) {
    union { h2 h; unsigned int u; } c; c.h = h; return c.u;
}
__device__ __forceinline__ unsigned int packh2(float a, float b) {
    union { h2 h; unsigned int u; } c;
    c.h = h2{(_Float16)a, (_Float16)b}; return c.u;
}
__device__ __forceinline__ h2 pkrtz(float a, float b) {
#if __has_builtin(__builtin_amdgcn_cvt_pkrtz)
    auto r = __builtin_amdgcn_cvt_pkrtz(a, b);
    return *reinterpret_cast<h2*>(&r);
#else
    return h2{(_Float16)a, (_Float16)b};
#endif
}
__device__ __forceinline__ float fdot2(h2 a, h2 b, float c) {
#if __has_builtin(__builtin_amdgcn_fdot2)
    return __builtin_amdgcn_fdot2(a, b, c, false);
#else
    return c + (float)a[0] * (float)b[0] + (float)a[1] * (float)b[1];
#endif
}
__device__ __forceinline__ h2 pkfma(h2 a, h2 b, h2 c) {
#if __has_builtin(__builtin_elementwise_fma)
    return __builtin_elementwise_fma(a, b, c);
#else
    return a * b + c;
#endif
}

// DPP helpers (VALU pipe, no DS traffic)
template<int CTRL>
__device__ __forceinline__ float dppmv(float x) {
    return __builtin_bit_cast(float,
        __builtin_amdgcn_update_dpp(0, __builtin_bit_cast(int, x), CTRL, 0xF, 0xF, true));
}
template<int IMM>
__device__ __forceinline__ float swz(float x) {
    return __builtin_bit_cast(float,
        __builtin_amdgcn_ds_swizzle(__builtin_bit_cast(int, x), IMM));
}
#define ROR1 0x121
#define ROR2 0x122
#define ROR4 0x124
#define ROR8 0x128
#define QXOR1 0xB1          // quad_perm [1,0,3,2]
#define SWZ_XOR16 0x401F    // ds_swizzle: xor 16 within 32-lane group
#define SWZ_BC8   0x0100    // ds_swizzle: all lanes read lane 8

__device__ __forceinline__ float sum32(float x) {
    x += dppmv<ROR1>(x); x += dppmv<ROR2>(x);
    x += dppmv<ROR4>(x); x += dppmv<ROR8>(x);
    return x + swz<SWZ_XOR16>(x);
}
__device__ __forceinline__ float sum16(float x) {
    x += dppmv<ROR1>(x); x += dppmv<ROR2>(x);
    x += dppmv<ROR4>(x); x += dppmv<ROR8>(x);
    return x;
}

// ---- prep: swizzle fuse_W, non_W, spatial_W into f16 MFMA B-fragments;
// f16-pair tables for query_W / token params.
// Fragment: n = ct*16 + (wl&15), k = ks*32 + (wl>>4)*8 + j, B[k][n] = W[n][k].
__global__ __launch_bounds__(256) void prep_w_kernel(
    const float* __restrict__ fuse_W, const float* __restrict__ non_W,
    const float* __restrict__ spatial_W, const float* __restrict__ query_W,
    const float* __restrict__ token_W, const float* __restrict__ token_b,
    unsigned short* __restrict__ ws)
{
    int id = blockIdx.x * 256 + threadIdx.x;
    if (id < 8192) {                       // fuse: 8 ks * 16 ct * 64 wl
        int wl = id & 63, ct = (id >> 6) & 15, ks = id >> 10;
        int n = ct * 16 + (wl & 15);
        int k0 = ks * 32 + (wl >> 4) * 8;
        const float* src = fuse_W + n * 256 + k0;
        float4 a = *reinterpret_cast<const float4*>(src);
        float4 b = *reinterpret_cast<const float4*>(src + 4);
        uint4 o = make_uint4(packh2(a.x, a.y), packh2(a.z, a.w),
                             packh2(b.x, b.y), packh2(b.z, b.w));
        reinterpret_cast<uint4*>(ws)[id] = o;
    } else if (id < 8704) {                // non_W: 8 ct * 64 wl, K pad 17->32
        int i = id - 8192;
        int wl = i & 63, ct = i >> 6;
        int n = ct * 16 + (wl & 15);
        int k0 = (wl >> 4) * 8;
        float v[8];
        #pragma unroll
        for (int j = 0; j < 8; ++j) {
            int k = k0 + j;
            v[j] = (k < 17) ? non_W[n * 17 + k] : 0.0f;
        }
        uint4 o = make_uint4(packh2(v[0], v[1]), packh2(v[2], v[3]),
                             packh2(v[4], v[5]), packh2(v[6], v[7]));
        reinterpret_cast<uint4*>(ws)[8192 + i] = o;
    } else if (id < 9216) {                // spatial_W: 8 ct * 64 wl, K=32
        int i = id - 8704;
        int wl = i & 63, ct = i >> 6;
        int n = ct * 16 + (wl & 15);
        int k0 = (wl >> 4) * 8;
        const float* src = spatial_W + n * 32 + k0;
        float4 a = *reinterpret_cast<const float4*>(src);
        float4 b = *reinterpret_cast<const float4*>(src + 4);
        uint4 o = make_uint4(packh2(a.x, a.y), packh2(a.z, a.w),
                             packh2(b.x, b.y), packh2(b.z, b.w));
        reinterpret_cast<uint4*>(ws)[8704 + i] = o;
    } else if (id < 9728) {                // qWh: 32 feat * 16 input-pairs
        int i = id - 9216;
        int feat = i >> 4, j = i & 15;
        int k0 = 2 * j, k1 = 2 * j + 1;
        float a = (k0 < 17) ? query_W[feat * 17 + k0] : 0.0f;
        float b = (k1 < 17) ? query_W[feat * 17 + k1] : 0.0f;
        unsigned int* qWh = reinterpret_cast<unsigned int*>(ws + 73728);
        qWh[i] = packh2(a, b);
    } else if (id < 9856) {                // TWb broadcast tables: 4 * 32
        int i = id - 9728;
        int tbl = i >> 5, k = i & 31;
        float v = (tbl < 3) ? token_W[3 * k + tbl] : token_b[k];
        unsigned int* TWb = reinterpret_cast<unsigned int*>(ws + 73728) + 512;
        TWb[i] = packh2(v, v);
    } else if (id < 9920) {                // TWp feature-pair tables: 4 * 16
        int i = id - 9856;
        int tbl = i >> 4, j = i & 15;
        int k0 = 2 * j, k1 = 2 * j + 1;
        float a = (tbl < 3) ? token_W[3 * k0 + tbl] : token_b[k0];
        float b = (tbl < 3) ? token_W[3 * k1 + tbl] : token_b[k1];
        unsigned int* TWp = reinterpret_cast<unsigned int*>(ws + 73728) + 640;
        TWp[i] = packh2(a, b);
    }
}

// ========= MONO: 32 rows/block, 256 threads, 4 rows per 32-lane group ========
__global__ __launch_bounds__(256, 4) void att_state_enc_kernel(
    const float* __restrict__ state,
    const float* __restrict__ query_b,
    const float* __restrict__ rbs_p, const float* __restrict__ vb_p, const float* __restrict__ ivb_p,
    const float* __restrict__ att_ln_w, const float* __restrict__ att_ln_b,
    const float* __restrict__ non_b,
    const float* __restrict__ spfb_W, const float* __restrict__ spfb_b,
    const float* __restrict__ sp_gate_p,
    const float* __restrict__ spatial_b,
    const unsigned short* __restrict__ Wf, const unsigned short* __restrict__ Wn,
    const unsigned short* __restrict__ Ws,
    const unsigned int* __restrict__ qWh, const unsigned int* __restrict__ TWb,
    const unsigned int* __restrict__ TWp,
    const float* __restrict__ fuse_b,
    const float* __restrict__ ln_w, const float* __restrict__ ln_b,
    float* __restrict__ out_x, float* __restrict__ out_tf)
{
    __shared__ __align__(16) float4 s_fb4[NROWS];
    __shared__ __align__(16) _Float16 s_na_h[NROWS][40];
    __shared__ __align__(16) _Float16 s_ctx_h[NROWS][40];
    __shared__ __align__(16) unsigned int s_q2[NROWS][16];
    __shared__ __align__(16) uint4 s_p4[NROWS][16];
    __shared__ __align__(16) _Float16 s_x[NROWS][280];
    __shared__ __align__(16) float2 s_part[NROWS][2];
    __shared__ __align__(16) float2 s_mr[NROWS];
    __shared__ float  s_tf[NROWS * 2];

    const int t = threadIdx.x;
    const int g = t >> 5;          // group 0..7; handles rows g, g+8, g+16, g+24
    const int l = t & 31;
    const long rowbase = (long)blockIdx.x * NROWS;

    const float rbs = rbs_p[0];
    const float vb  = vb_p[0];
    const float ivb = ivb_p[0];
    const float qb = query_b[l];
    const uint4* qwp = reinterpret_cast<const uint4*>(qWh + l * 16);
    const uint4 qw0 = qwp[0], qw1 = qwp[1], qw2 = qwp[2];
    const h2 zero2 = h2{(_Float16)0.0f, (_Float16)0.0f};
    const unsigned long long halfmask =
        0xFFFFFFFFull << (((unsigned)t & 32u));   // lanes 0-31 or 32-63 of wave

    // ========== per-row front-end: 4 independent rows per group ==============
    #pragma unroll
    for (int rr = 0; rr < 4; ++rr) {
        const int row = g + 8 * rr;
        const long gb = (rowbase + row) * DSTATE;

        // -- phase 2: loads + stats --
        float sec = state[gb + l];
        float dif = state[gb + 32 + l];
        float nl  = (l < 11) ? state[gb + 64 + l] : 0.0f;
        float vld = (sec < 0.95f) ? 1.0f : 0.0f;
        float da  = fabsf(dif);
        float vs = (float)__popcll(__ballot(sec < 0.95f) & halfmask);
        float mn = sec, sm = sec, ds = da, dmx = da;
        {
            mn = fminf(mn, dppmv<ROR1>(mn)); sm += dppmv<ROR1>(sm);
            ds += dppmv<ROR1>(ds); dmx = fmaxf(dmx, dppmv<ROR1>(dmx));
            mn = fminf(mn, dppmv<ROR2>(mn)); sm += dppmv<ROR2>(sm);
            ds += dppmv<ROR2>(ds); dmx = fmaxf(dmx, dppmv<ROR2>(dmx));
            mn = fminf(mn, dppmv<ROR4>(mn)); sm += dppmv<ROR4>(sm);
            ds += dppmv<ROR4>(ds); dmx = fmaxf(dmx, dppmv<ROR4>(dmx));
            mn = fminf(mn, dppmv<ROR8>(mn)); sm += dppmv<ROR8>(sm);
            ds += dppmv<ROR8>(ds); dmx = fmaxf(dmx, dppmv<ROR8>(dmx));
            mn = fminf(mn, swz<SWZ_XOR16>(mn)); sm += swz<SWZ_XOR16>(sm);
            ds += swz<SWZ_XOR16>(ds);
            dmx = fmaxf(dmx, swz<SWZ_XOR16>(dmx));
        }
        const float min_r = mn, mean_r = sm * (1.0f/32.0f), vr = vs * (1.0f/32.0f);
        const float dam = ds * (1.0f/32.0f), dax = dmx;
        const float dyaw = fminf(fabsf(swz<SWZ_BC8>(nl)), 1.0f);

        float naval = 0.0f;
        if (l < 11)       naval = nl;
        else if (l == 11) naval = min_r;
        else if (l == 12) naval = mean_r;
        else if (l == 13) naval = vr;
        else if (l == 14) naval = dam;
        else if (l == 15) naval = dax;
        else if (l == 16) naval = dyaw;
        s_na_h[row][l] = (_Float16)naval;
        if (l == 0) {
            s_fb4[row] = make_float4(min_r, mean_r, vr, 0.0f);
            s_tf[row * 2] = fminf(dam, 1.0f); s_tf[row * 2 + 1] = dyaw;
        }

        // -- phase 3: q = relu(query_W @ na) via fdot2; lane = feature --
        {
            const uint4* nap = reinterpret_cast<const uint4*>(&s_na_h[row][0]);
            uint4 n0 = nap[0], n1 = nap[1], n2 = nap[2];
            float a0 = qb, a1 = 0.0f;
            a0 = fdot2(u2h(qw0.x), u2h(n0.x), a0);
            a1 = fdot2(u2h(qw0.y), u2h(n0.y), a1);
            a0 = fdot2(u2h(qw0.z), u2h(n0.z), a0);
            a1 = fdot2(u2h(qw0.w), u2h(n0.w), a1);
            a0 = fdot2(u2h(qw1.x), u2h(n1.x), a0);
            a1 = fdot2(u2h(qw1.y), u2h(n1.y), a1);
            a0 = fdot2(u2h(qw1.z), u2h(n1.z), a0);
            a1 = fdot2(u2h(qw1.w), u2h(n1.w), a1);
            a0 = fdot2(u2h(qw2.x), u2h(n2.x), a0);
            float qv = fmaxf(a0 + a1, 0.0f);
            float qn = dppmv<QXOR1>(qv);
            if ((l & 1) == 0) s_q2[row][l >> 1] = h2u(pkrtz(qv, qn));
        }

        // -- phase 4: score + softmax (packed f16 feature pairs) --
        {
            unsigned int q2[16];
            *reinterpret_cast<uint4*>(&q2[0])  = *reinterpret_cast<const uint4*>(&s_q2[row][0]);
            *reinterpret_cast<uint4*>(&q2[4])  = *reinterpret_cast<const uint4*>(&s_q2[row][4]);
            *reinterpret_cast<uint4*>(&q2[8])  = *reinterpret_cast<const uint4*>(&s_q2[row][8]);
            *reinterpret_cast<uint4*>(&q2[12]) = *reinterpret_cast<const uint4*>(&s_q2[row][12]);
            const h2 sec2 = pkrtz(sec, sec);
            const h2 dif2 = pkrtz(dif, dif);
            const h2 vld2 = pkrtz(vld, vld);
            float a0 = 0.0f, a1 = 0.0f;
            #pragma unroll
            for (int j = 0; j < 16; j += 2) {
                h2 z0 = pkfma(vld2, u2h(TWp[32 + j]), u2h(TWp[48 + j]));
                z0 = pkfma(dif2, u2h(TWp[16 + j]), z0);
                z0 = pkfma(sec2, u2h(TWp[j]), z0);
                z0 = __builtin_elementwise_max(z0, zero2);
                a0 = fdot2(z0, u2h(q2[j]), a0);
                h2 z1 = pkfma(vld2, u2h(TWp[33 + j]), u2h(TWp[49 + j]));
                z1 = pkfma(dif2, u2h(TWp[17 + j]), z1);
                z1 = pkfma(sec2, u2h(TWp[1 + j]), z1);
                z1 = __builtin_elementwise_max(z1, zero2);
                a1 = fdot2(z1, u2h(q2[j + 1]), a1);
            }
            float score = (a0 + a1) * 0.17677669529663687f
                        + rbs * (1.0f - sec) + vb * vld + ivb * (1.0f - vld);
            score = fminf(fmaxf(score, -60.0f), 60.0f);
            float e = __expf(score - 20.0f);
            float se = sum32(e);
            float w = __fdividef(e, se);
            float wn = dppmv<QXOR1>(w);
            float sn = dppmv<QXOR1>(sec);
            float dn = dppmv<QXOR1>(dif);
            float vn = dppmv<QXOR1>(vld);
            if ((l & 1) == 0) {
                uint4 pk = make_uint4(h2u(pkrtz(w, wn)), h2u(pkrtz(sec, sn)),
                                      h2u(pkrtz(dif, dn)), h2u(pkrtz(vld, vn)));
                s_p4[row][l >> 1] = pk;
            }
        }

        // -- phase 5: ctx + LN32 (packed f16, fused sum/sumsq reduce) --
        {
            const h2 tw0b = u2h(TWb[l]);
            const h2 tw1b = u2h(TWb[32 + l]);
            const h2 tw2b = u2h(TWb[64 + l]);
            const h2 tbb  = u2h(TWb[96 + l]);
            float a0 = 0.0f, a1 = 0.0f;
            #pragma unroll
            for (int i = 0; i < 16; i += 2) {
                uint4 p0 = s_p4[row][i];
                h2 z0 = pkfma(u2h(p0.w), tw2b, tbb);
                z0 = pkfma(u2h(p0.z), tw1b, z0);
                z0 = pkfma(u2h(p0.y), tw0b, z0);
                z0 = __builtin_elementwise_max(z0, zero2);
                a0 = fdot2(u2h(p0.x), z0, a0);
                uint4 p1 = s_p4[row][i + 1];
                h2 z1 = pkfma(u2h(p1.w), tw2b, tbb);
                z1 = pkfma(u2h(p1.z), tw1b, z1);
                z1 = pkfma(u2h(p1.y), tw0b, z1);
                z1 = __builtin_elementwise_max(z1, zero2);
                a1 = fdot2(u2h(p1.x), z1, a1);
            }
            float acc = a0 + a1;
            float smv = acc, sq = acc * acc;
            smv += dppmv<ROR1>(smv); sq += dppmv<ROR1>(sq);
            smv += dppmv<ROR2>(smv); sq += dppmv<ROR2>(sq);
            smv += dppmv<ROR4>(smv); sq += dppmv<ROR4>(sq);
            smv += dppmv<ROR8>(smv); sq += dppmv<ROR8>(sq);
            smv += swz<SWZ_XOR16>(smv); sq += swz<SWZ_XOR16>(sq);
            float mean = smv * (1.0f/32.0f);
            float var  = sq * (1.0f/32.0f) - mean * mean;
            float rstd = rsqrtf(var + 1e-5f);
            float ctx = (acc - mean) * rstd * att_ln_w[l] + att_ln_b[l];
            s_ctx_h[row][l] = (_Float16)ctx;
        }
    }
    __syncthreads();   // BARRIER 1

    const int wid = t >> 6, wl = t & 63;     // wave 0..3
    const int arow = wl & 15, kg = wl >> 4;
    const int m = wid & 1, cqb = wid >> 1;   // row half 0/1, col half 0/1
    const int rbase = m * 16;

    // ================= phase B: non_emb + sp_emb via MFMA (f16) =============
    {
        if (t < NROWS * 2) out_tf[rowbase * 2 + t] = s_tf[t];

        const float alpha = 1.0f / (1.0f + __expf(-sp_gate_p[0]));
        f16x8 a_na  = *reinterpret_cast<const f16x8*>(&s_na_h[rbase + arow][kg * 8]);
        f16x8 a_ctx = *reinterpret_cast<const f16x8*>(&s_ctx_h[rbase + arow][kg * 8]);
        float mnr[4], mer[4], vrr[4];
        #pragma unroll
        for (int r = 0; r < 4; ++r) {
            float4 fb4 = s_fb4[rbase + kg * 4 + r];
            mnr[r] = fb4.x; mer[r] = fb4.y; vrr[r] = fb4.z;
        }
        #pragma unroll
        for (int tt = 0; tt < 4; ++tt) {
            const int ct = cqb * 4 + tt;             // 0..7
            const int col = ct * 16 + arow;          // 0..127
            f16x8 bN = *reinterpret_cast<const f16x8*>(Wn + ((ct * 64) + wl) * 8);
            f16x8 bS = *reinterpret_cast<const f16x8*>(Ws + ((ct * 64) + wl) * 8);
            f32x4 accN = __builtin_amdgcn_mfma_f32_16x16x32_f16(a_na,  bN, f32x4{0.f,0.f,0.f,0.f}, 0,0,0);
            f32x4 accS = __builtin_amdgcn_mfma_f32_16x16x32_f16(a_ctx, bS, f32x4{0.f,0.f,0.f,0.f}, 0,0,0);
            const float nb = non_b[col], sb = spatial_b[col];
            const float w0 = spfb_W[col*3], w1 = spfb_W[col*3+1], w2 = spfb_W[col*3+2];
            const float fbb = spfb_b[col];
            #pragma unroll
            for (int r = 0; r < 4; ++r) {
                const int row = rbase + kg * 4 + r;
                float ne = fmaxf(accN[r] + nb, 0.0f);
                float sa = fmaxf(accS[r] + sb, 0.0f);
                float fb = fmaxf(fbb + w0*mnr[r] + w1*mer[r] + w2*vrr[r], 0.0f);
                float sp = alpha * sa + (1.0f - alpha) * fb;
                float nen = dppmv<QXOR1>(ne);
                float spn = dppmv<QXOR1>(sp);
                if ((arow & 1) == 0) {
                    *reinterpret_cast<unsigned int*>(&s_x[row][col])       = h2u(pkrtz(ne, nen));
                    *reinterpret_cast<unsigned int*>(&s_x[row][128 + col]) = h2u(pkrtz(sp, spn));
                }
            }
        }
    }
    __syncthreads();   // BARRIER 2

    // ================= phase C: fuse GEMM (MFMA f16) + LN partials ==========
    float v[8][4];
    {
        f32x4 acc[8];
        #pragma unroll
        for (int i = 0; i < 8; ++i) acc[i] = f32x4{0.f, 0.f, 0.f, 0.f};
        #pragma unroll
        for (int ks = 0; ks < 8; ++ks) {
            f16x8 a = *reinterpret_cast<const f16x8*>(&s_x[rbase + arow][ks * 32 + kg * 8]);
            #pragma unroll
            for (int i = 0; i < 8; ++i) {
                const int ct = cqb * 8 + i;          // 0..15
                f16x8 b = *reinterpret_cast<const f16x8*>(Wf + (((ks * 16 + ct) * 64) + wl) * 8);
                acc[i] = __builtin_amdgcn_mfma_f32_16x16x32_f16(a, b, acc[i], 0, 0, 0);
            }
        }
        float psum[4] = {0.f, 0.f, 0.f, 0.f};
        float psq[4]  = {0.f, 0.f, 0.f, 0.f};
        #pragma unroll
        for (int i = 0; i < 8; ++i) {
            const int col = (cqb * 8 + i) * 16 + arow;
            const float bias = fuse_b[col];
            #pragma unroll
            for (int r = 0; r < 4; ++r) {
                float x = fmaxf(acc[i][r] + bias, 0.0f);
                v[i][r] = x;
                psum[r] += x;
                psq[r]  += x * x;
            }
        }
        #pragma unroll
        for (int r = 0; r < 4; ++r) {
            psum[r] = sum16(psum[r]);
            psq[r]  = sum16(psq[r]);
        }
        if (arow == 0) {
            #pragma unroll
            for (int r = 0; r < 4; ++r)
                s_part[rbase + kg * 4 + r][cqb] = make_float2(psum[r], psq[r]);
        }
    }
    __syncthreads();   // BARRIER 3

    // ================= phase C2: per-row LN stats (32 threads) ==============
    if (t < NROWS) {
        float4 pa = *reinterpret_cast<const float4*>(&s_part[t][0]);
        float sum = pa.x + pa.z;
        float sq  = pa.y + pa.w;
        float mean = sum * (1.0f/256.0f);
        float var  = sq * (1.0f/256.0f) - mean * mean;
        float rstd = rsqrtf(var + 1e-5f);
        s_mr[t] = make_float2(mean, rstd);
    }
    __syncthreads();   // BARRIER 4

    // ================= phase D: LN + store ==================================
    {
        #pragma unroll
        for (int r = 0; r < 4; ++r) {
            const int row = rbase + kg * 4 + r;
            float2 mr = s_mr[row];
            const long obase = (rowbase + row) * EMBD;
            #pragma unroll
            for (int i = 0; i < 8; ++i) {
                const int col = (cqb * 8 + i) * 16 + arow;
                out_x[obase + col] = (v[i][r] - mr.x) * mr.y * ln_w[col] + ln_b[col];
            }
        }
    }
}

extern "C" void kernel_launch(void* const* d_in, const int* in_sizes, int n_in,
                              void* d_out, int out_size, void* d_ws, size_t ws_size,
                              hipStream_t stream) {
    const float* state     = (const float*)d_in[0];
    const float* token_W   = (const float*)d_in[1];
    const float* token_b   = (const float*)d_in[2];
    const float* query_W   = (const float*)d_in[3];
    const float* query_b   = (const float*)d_in[4];
    const float* rbs       = (const float*)d_in[5];
    const float* vbias     = (const float*)d_in[6];
    const float* ivbias    = (const float*)d_in[7];
    const float* att_ln_w  = (const float*)d_in[8];
    const float* att_ln_b  = (const float*)d_in[9];
    const float* non_W     = (const float*)d_in[10];
    const float* non_b     = (const float*)d_in[11];
    const float* spfb_W    = (const float*)d_in[12];
    const float* spfb_b    = (const float*)d_in[13];
    const float* sp_gate   = (const float*)d_in[14];
    const float* spatial_W = (const float*)d_in[15];
    const float* spatial_b = (const float*)d_in[16];
    const float* fuse_W    = (const float*)d_in[17];
    const float* fuse_b    = (const float*)d_in[18];
    const float* ln_w      = (const float*)d_in[19];
    const float* ln_b      = (const float*)d_in[20];

    float* out_x  = (float*)d_out;
    float* out_tf = out_x + (size_t)BH * EMBD;

    unsigned short* wsu = (unsigned short*)d_ws;
    const unsigned short* Wf = wsu;                  // 65536 f16
    const unsigned short* Wn = wsu + 65536;          // 4096 f16
    const unsigned short* Ws = wsu + 65536 + 4096;   // 4096 f16
    const unsigned int* qWh = (const unsigned int*)(wsu + 73728);   // 512
    const unsigned int* TWb = qWh + 512;                            // 128
    const unsigned int* TWp = TWb + 128;                            // 64

    hipLaunchKernelGGL(prep_w_kernel, dim3(39), dim3(256), 0, stream,
                       fuse_W, non_W, spatial_W, query_W, token_W, token_b, wsu);

    hipLaunchKernelGGL(att_state_enc_kernel, dim3(NBLOCKS), dim3(NTHREADS), 0, stream,
        state, query_b, rbs, vbias, ivbias,
        att_ln_w, att_ln_b, non_b, spfb_W, spfb_b, sp_gate, spatial_b,
        Wf, Wn, Ws, qWh, TWb, TWp, fuse_b, ln_w, ln_b, out_x, out_tf);
}

// Round 12
// 51.451 us; speedup vs baseline: 1.0677x; 1.0677x over previous
//
#include <hip/hip_runtime.h>

// Problem constants
#define BH      65536     // B*H
#define DSTATE  75
#define EMBD    256
#define NROWS   32        // rows per block; 2 rows per 32-lane group
#define NTHREADS 512
#define NBLOCKS (BH / NROWS)   // 2048

typedef _Float16 h2    __attribute__((ext_vector_type(2)));
typedef _Float16 f16x8 __attribute__((ext_vector_type(8)));
typedef float    f32x4 __attribute__((ext_vector_type(4)));

__device__ __forceinline__ h2 u2h(unsigned int u) {
    union { unsigned int u; h2 h; } c; c.u = u; return c.h;
}
__device__ __forceinline__ unsigned int h2u(h2 h) {
    union { h2 h; unsigned int u; } c; c.h = h; return c.u;
}
__device__ __forceinline__ unsigned int packh2(float a, float b) {
    union { h2 h; unsigned int u; } c;
    c.h = h2{(_Float16)a, (_Float16)b}; return c.u;
}
__device__ __forceinline__ h2 pkrtz(float a, float b) {
#if __has_builtin(__builtin_amdgcn_cvt_pkrtz)
    auto r = __builtin_amdgcn_cvt_pkrtz(a, b);
    return *reinterpret_cast<h2*>(&r);
#else
    return h2{(_Float16)a, (_Float16)b};
#endif
}
__device__ __forceinline__ float fdot2(h2 a, h2 b, float c) {
#if __has_builtin(__builtin_amdgcn_fdot2)
    return __builtin_amdgcn_fdot2(a, b, c, false);
#else
    return c + (float)a[0] * (float)b[0] + (float)a[1] * (float)b[1];
#endif
}
__device__ __forceinline__ h2 pkfma(h2 a, h2 b, h2 c) {
#if __has_builtin(__builtin_elementwise_fma)
    return __builtin_elementwise_fma(a, b, c);
#else
    return a * b + c;
#endif
}

// DPP helpers (VALU pipe, no DS traffic)
template<int CTRL>
__device__ __forceinline__ float dppmv(float x) {
    return __builtin_bit_cast(float,
        __builtin_amdgcn_update_dpp(0, __builtin_bit_cast(int, x), CTRL, 0xF, 0xF, true));
}
template<int IMM>
__device__ __forceinline__ float swz(float x) {
    return __builtin_bit_cast(float,
        __builtin_amdgcn_ds_swizzle(__builtin_bit_cast(int, x), IMM));
}
#define ROR1 0x121
#define ROR2 0x122
#define ROR4 0x124
#define ROR8 0x128
#define QXOR1 0xB1          // quad_perm [1,0,3,2]
#define SWZ_XOR16 0x401F    // ds_swizzle: xor 16 within 32-lane group
#define SWZ_BC8   0x0100    // ds_swizzle: all lanes read lane 8

__device__ __forceinline__ float sum32(float x) {
    x += dppmv<ROR1>(x); x += dppmv<ROR2>(x);
    x += dppmv<ROR4>(x); x += dppmv<ROR8>(x);
    return x + swz<SWZ_XOR16>(x);
}
__device__ __forceinline__ float sum16(float x) {
    x += dppmv<ROR1>(x); x += dppmv<ROR2>(x);
    x += dppmv<ROR4>(x); x += dppmv<ROR8>(x);
    return x;
}

// ---- prep: swizzle fuse_W, non_W, spatial_W into f16 MFMA B-fragments;
// f16-pair tables for query_W / token params.
// Fragment: n = ct*16 + (wl&15), k = ks*32 + (wl>>4)*8 + j, B[k][n] = W[n][k].
__global__ __launch_bounds__(256) void prep_w_kernel(
    const float* __restrict__ fuse_W, const float* __restrict__ non_W,
    const float* __restrict__ spatial_W, const float* __restrict__ query_W,
    const float* __restrict__ token_W, const float* __restrict__ token_b,
    unsigned short* __restrict__ ws)
{
    int id = blockIdx.x * 256 + threadIdx.x;
    if (id < 8192) {                       // fuse: 8 ks * 16 ct * 64 wl
        int wl = id & 63, ct = (id >> 6) & 15, ks = id >> 10;
        int n = ct * 16 + (wl & 15);
        int k0 = ks * 32 + (wl >> 4) * 8;
        const float* src = fuse_W + n * 256 + k0;
        float4 a = *reinterpret_cast<const float4*>(src);
        float4 b = *reinterpret_cast<const float4*>(src + 4);
        uint4 o = make_uint4(packh2(a.x, a.y), packh2(a.z, a.w),
                             packh2(b.x, b.y), packh2(b.z, b.w));
        reinterpret_cast<uint4*>(ws)[id] = o;
    } else if (id < 8704) {                // non_W: 8 ct * 64 wl, K pad 17->32
        int i = id - 8192;
        int wl = i & 63, ct = i >> 6;
        int n = ct * 16 + (wl & 15);
        int k0 = (wl >> 4) * 8;
        float v[8];
        #pragma unroll
        for (int j = 0; j < 8; ++j) {
            int k = k0 + j;
            v[j] = (k < 17) ? non_W[n * 17 + k] : 0.0f;
        }
        uint4 o = make_uint4(packh2(v[0], v[1]), packh2(v[2], v[3]),
                             packh2(v[4], v[5]), packh2(v[6], v[7]));
        reinterpret_cast<uint4*>(ws)[8192 + i] = o;
    } else if (id < 9216) {                // spatial_W: 8 ct * 64 wl, K=32
        int i = id - 8704;
        int wl = i & 63, ct = i >> 6;
        int n = ct * 16 + (wl & 15);
        int k0 = (wl >> 4) * 8;
        const float* src = spatial_W + n * 32 + k0;
        float4 a = *reinterpret_cast<const float4*>(src);
        float4 b = *reinterpret_cast<const float4*>(src + 4);
        uint4 o = make_uint4(packh2(a.x, a.y), packh2(a.z, a.w),
                             packh2(b.x, b.y), packh2(b.z, b.w));
        reinterpret_cast<uint4*>(ws)[8704 + i] = o;
    } else if (id < 9728) {                // qWh: 32 feat * 16 input-pairs
        int i = id - 9216;
        int feat = i >> 4, j = i & 15;
        int k0 = 2 * j, k1 = 2 * j + 1;
        float a = (k0 < 17) ? query_W[feat * 17 + k0] : 0.0f;
        float b = (k1 < 17) ? query_W[feat * 17 + k1] : 0.0f;
        unsigned int* qWh = reinterpret_cast<unsigned int*>(ws + 73728);
        qWh[i] = packh2(a, b);
    } else if (id < 9856) {                // TWb broadcast tables: 4 * 32
        int i = id - 9728;
        int tbl = i >> 5, k = i & 31;
        float v = (tbl < 3) ? token_W[3 * k + tbl] : token_b[k];
        unsigned int* TWb = reinterpret_cast<unsigned int*>(ws + 73728) + 512;
        TWb[i] = packh2(v, v);
    } else if (id < 9920) {                // TWp feature-pair tables: 4 * 16
        int i = id - 9856;
        int tbl = i >> 4, j = i & 15;
        int k0 = 2 * j, k1 = 2 * j + 1;
        float a = (tbl < 3) ? token_W[3 * k0 + tbl] : token_b[k0];
        float b = (tbl < 3) ? token_W[3 * k1 + tbl] : token_b[k1];
        unsigned int* TWp = reinterpret_cast<unsigned int*>(ws + 73728) + 640;
        TWp[i] = packh2(a, b);
    }
}

// ========= MONO: 32 rows/block, 512 threads, phase-interleaved dual chains ===
__global__ __launch_bounds__(512, 4) void att_state_enc_kernel(
    const float* __restrict__ state,
    const float* __restrict__ query_b,
    const float* __restrict__ rbs_p, const float* __restrict__ vb_p, const float* __restrict__ ivb_p,
    const float* __restrict__ att_ln_w, const float* __restrict__ att_ln_b,
    const float* __restrict__ non_b,
    const float* __restrict__ spfb_W, const float* __restrict__ spfb_b,
    const float* __restrict__ sp_gate_p,
    const float* __restrict__ spatial_b,
    const unsigned short* __restrict__ Wf, const unsigned short* __restrict__ Wn,
    const unsigned short* __restrict__ Ws,
    const unsigned int* __restrict__ qWh, const unsigned int* __restrict__ TWb,
    const unsigned int* __restrict__ TWp,
    const float* __restrict__ fuse_b,
    const float* __restrict__ ln_w, const float* __restrict__ ln_b,
    float* __restrict__ out_x, float* __restrict__ out_tf)
{
    __shared__ __align__(16) float4 s_fb4[NROWS];
    __shared__ __align__(16) _Float16 s_na_h[NROWS][40];
    __shared__ __align__(16) _Float16 s_ctx_h[NROWS][40];
    __shared__ __align__(16) unsigned int s_q2[NROWS][16];
    __shared__ __align__(16) uint4 s_p4[NROWS][16];
    __shared__ __align__(16) _Float16 s_x[NROWS][280];
    __shared__ __align__(16) float2 s_part[NROWS][4];
    __shared__ __align__(16) float2 s_mr[NROWS];
    __shared__ float  s_tf[NROWS * 2];

    const int t = threadIdx.x;
    const int g = t >> 5;          // group 0..15; handles rows g and g+16
    const int l = t & 31;
    const long rowbase = (long)blockIdx.x * NROWS;

    const float rbs = rbs_p[0];
    const float vb  = vb_p[0];
    const float ivb = ivb_p[0];
    const float qb = query_b[l];
    const uint4* qwp = reinterpret_cast<const uint4*>(qWh + l * 16);
    const uint4 qw0 = qwp[0], qw1 = qwp[1], qw2 = qwp[2];
    const h2 zero2 = h2{(_Float16)0.0f, (_Float16)0.0f};
    const unsigned long long halfmask =
        0xFFFFFFFFull << (((unsigned)t & 32u));   // lanes 0-31 or 32-63 of wave

    // ---------- phase 2a: issue BOTH rows' global loads up front ----------
    float sec[2], dif[2], nl[2];
    #pragma unroll
    for (int rr = 0; rr < 2; ++rr) {
        const long gb = (rowbase + g + 16 * rr) * DSTATE;
        sec[rr] = state[gb + l];
        dif[rr] = state[gb + 32 + l];
        nl[rr]  = (l < 11) ? state[gb + 64 + l] : 0.0f;
    }

    // ---------- phase 2b: stats, both chains adjacent ----------
    float vld[2], min_r[2], mean_r[2], vr[2], dam[2], dax[2], dyaw[2];
    #pragma unroll
    for (int rr = 0; rr < 2; ++rr) {
        vld[rr] = (sec[rr] < 0.95f) ? 1.0f : 0.0f;
        float vs = (float)__popcll(__ballot(sec[rr] < 0.95f) & halfmask);
        float da = fabsf(dif[rr]);
        float mn = sec[rr], sm = sec[rr], ds = da, dmx = da;
        mn = fminf(mn, dppmv<ROR1>(mn)); sm += dppmv<ROR1>(sm);
        ds += dppmv<ROR1>(ds); dmx = fmaxf(dmx, dppmv<ROR1>(dmx));
        mn = fminf(mn, dppmv<ROR2>(mn)); sm += dppmv<ROR2>(sm);
        ds += dppmv<ROR2>(ds); dmx = fmaxf(dmx, dppmv<ROR2>(dmx));
        mn = fminf(mn, dppmv<ROR4>(mn)); sm += dppmv<ROR4>(sm);
        ds += dppmv<ROR4>(ds); dmx = fmaxf(dmx, dppmv<ROR4>(dmx));
        mn = fminf(mn, dppmv<ROR8>(mn)); sm += dppmv<ROR8>(sm);
        ds += dppmv<ROR8>(ds); dmx = fmaxf(dmx, dppmv<ROR8>(dmx));
        mn = fminf(mn, swz<SWZ_XOR16>(mn)); sm += swz<SWZ_XOR16>(sm);
        ds += swz<SWZ_XOR16>(ds);
        dmx = fmaxf(dmx, swz<SWZ_XOR16>(dmx));
        min_r[rr] = mn; mean_r[rr] = sm * (1.0f/32.0f); vr[rr] = vs * (1.0f/32.0f);
        dam[rr] = ds * (1.0f/32.0f); dax[rr] = dmx;
        dyaw[rr] = fminf(fabsf(swz<SWZ_BC8>(nl[rr])), 1.0f);
    }

    // ---------- phase 2c: na / fb / tf writes, both rows ----------
    #pragma unroll
    for (int rr = 0; rr < 2; ++rr) {
        const int row = g + 16 * rr;
        float naval = 0.0f;
        if (l < 11)       naval = nl[rr];
        else if (l == 11) naval = min_r[rr];
        else if (l == 12) naval = mean_r[rr];
        else if (l == 13) naval = vr[rr];
        else if (l == 14) naval = dam[rr];
        else if (l == 15) naval = dax[rr];
        else if (l == 16) naval = dyaw[rr];
        s_na_h[row][l] = (_Float16)naval;
        if (l == 0) {
            s_fb4[row] = make_float4(min_r[rr], mean_r[rr], vr[rr], 0.0f);
            s_tf[row * 2] = fminf(dam[rr], 1.0f); s_tf[row * 2 + 1] = dyaw[rr];
        }
    }

    // ---------- phase 3: q for both rows ----------
    #pragma unroll
    for (int rr = 0; rr < 2; ++rr) {
        const int row = g + 16 * rr;
        const uint4* nap = reinterpret_cast<const uint4*>(&s_na_h[row][0]);
        uint4 n0 = nap[0], n1 = nap[1], n2 = nap[2];
        float a0 = qb, a1 = 0.0f;
        a0 = fdot2(u2h(qw0.x), u2h(n0.x), a0);
        a1 = fdot2(u2h(qw0.y), u2h(n0.y), a1);
        a0 = fdot2(u2h(qw0.z), u2h(n0.z), a0);
        a1 = fdot2(u2h(qw0.w), u2h(n0.w), a1);
        a0 = fdot2(u2h(qw1.x), u2h(n1.x), a0);
        a1 = fdot2(u2h(qw1.y), u2h(n1.y), a1);
        a0 = fdot2(u2h(qw1.z), u2h(n1.z), a0);
        a1 = fdot2(u2h(qw1.w), u2h(n1.w), a1);
        a0 = fdot2(u2h(qw2.x), u2h(n2.x), a0);
        float qv = fmaxf(a0 + a1, 0.0f);
        float qn = dppmv<QXOR1>(qv);
        if ((l & 1) == 0) s_q2[row][l >> 1] = h2u(pkrtz(qv, qn));
    }

    // ---------- phase 4: score + softmax for both rows ----------
    #pragma unroll
    for (int rr = 0; rr < 2; ++rr) {
        const int row = g + 16 * rr;
        unsigned int q2[16];
        *reinterpret_cast<uint4*>(&q2[0])  = *reinterpret_cast<const uint4*>(&s_q2[row][0]);
        *reinterpret_cast<uint4*>(&q2[4])  = *reinterpret_cast<const uint4*>(&s_q2[row][4]);
        *reinterpret_cast<uint4*>(&q2[8])  = *reinterpret_cast<const uint4*>(&s_q2[row][8]);
        *reinterpret_cast<uint4*>(&q2[12]) = *reinterpret_cast<const uint4*>(&s_q2[row][12]);
        const h2 sec2 = pkrtz(sec[rr], sec[rr]);
        const h2 dif2 = pkrtz(dif[rr], dif[rr]);
        const h2 vld2 = pkrtz(vld[rr], vld[rr]);
        float a0 = 0.0f, a1 = 0.0f;
        #pragma unroll
        for (int j = 0; j < 16; j += 2) {
            h2 z0 = pkfma(vld2, u2h(TWp[32 + j]), u2h(TWp[48 + j]));
            z0 = pkfma(dif2, u2h(TWp[16 + j]), z0);
            z0 = pkfma(sec2, u2h(TWp[j]), z0);
            z0 = __builtin_elementwise_max(z0, zero2);
            a0 = fdot2(z0, u2h(q2[j]), a0);
            h2 z1 = pkfma(vld2, u2h(TWp[33 + j]), u2h(TWp[49 + j]));
            z1 = pkfma(dif2, u2h(TWp[17 + j]), z1);
            z1 = pkfma(sec2, u2h(TWp[1 + j]), z1);
            z1 = __builtin_elementwise_max(z1, zero2);
            a1 = fdot2(z1, u2h(q2[j + 1]), a1);
        }
        float score = (a0 + a1) * 0.17677669529663687f
                    + rbs * (1.0f - sec[rr]) + vb * vld[rr] + ivb * (1.0f - vld[rr]);
        score = fminf(fmaxf(score, -60.0f), 60.0f);
        float e = __expf(score - 20.0f);
        float se = sum32(e);
        float w = __fdividef(e, se);
        float wn = dppmv<QXOR1>(w);
        float sn = dppmv<QXOR1>(sec[rr]);
        float dn = dppmv<QXOR1>(dif[rr]);
        float vn = dppmv<QXOR1>(vld[rr]);
        if ((l & 1) == 0) {
            uint4 pk = make_uint4(h2u(pkrtz(w, wn)), h2u(pkrtz(sec[rr], sn)),
                                  h2u(pkrtz(dif[rr], dn)), h2u(pkrtz(vld[rr], vn)));
            s_p4[row][l >> 1] = pk;
        }
    }

    // ---------- phase 5: ctx + LN32 for both rows ----------
    {
        const h2 tw0b = u2h(TWb[l]);
        const h2 tw1b = u2h(TWb[32 + l]);
        const h2 tw2b = u2h(TWb[64 + l]);
        const h2 tbb  = u2h(TWb[96 + l]);
        const float alw = att_ln_w[l], alb = att_ln_b[l];
        #pragma unroll
        for (int rr = 0; rr < 2; ++rr) {
            const int row = g + 16 * rr;
            float a0 = 0.0f, a1 = 0.0f;
            #pragma unroll
            for (int i = 0; i < 16; i += 2) {
                uint4 p0 = s_p4[row][i];
                h2 z0 = pkfma(u2h(p0.w), tw2b, tbb);
                z0 = pkfma(u2h(p0.z), tw1b, z0);
                z0 = pkfma(u2h(p0.y), tw0b, z0);
                z0 = __builtin_elementwise_max(z0, zero2);
                a0 = fdot2(u2h(p0.x), z0, a0);
                uint4 p1 = s_p4[row][i + 1];
                h2 z1 = pkfma(u2h(p1.w), tw2b, tbb);
                z1 = pkfma(u2h(p1.z), tw1b, z1);
                z1 = pkfma(u2h(p1.y), tw0b, z1);
                z1 = __builtin_elementwise_max(z1, zero2);
                a1 = fdot2(u2h(p1.x), z1, a1);
            }
            float acc = a0 + a1;
            float smv = acc, sq = acc * acc;
            smv += dppmv<ROR1>(smv); sq += dppmv<ROR1>(sq);
            smv += dppmv<ROR2>(smv); sq += dppmv<ROR2>(sq);
            smv += dppmv<ROR4>(smv); sq += dppmv<ROR4>(sq);
            smv += dppmv<ROR8>(smv); sq += dppmv<ROR8>(sq);
            smv += swz<SWZ_XOR16>(smv); sq += swz<SWZ_XOR16>(sq);
            float mean = smv * (1.0f/32.0f);
            float var  = sq * (1.0f/32.0f) - mean * mean;
            float rstd = rsqrtf(var + 1e-5f);
            float ctx = (acc - mean) * rstd * alw + alb;
            s_ctx_h[row][l] = (_Float16)ctx;
        }
    }
    __syncthreads();   // BARRIER 1

    const int wid = t >> 6, wl = t & 63;
    const int arow = wl & 15, kg = wl >> 4;
    const int m = wid & 1, cq = wid >> 1;       // row-half 0/1, col quarter 0..3

    // ================= phase B: non_emb + sp_emb via MFMA (f16) =============
    {
        if (t < NROWS * 2) out_tf[rowbase * 2 + t] = s_tf[t];

        const float alpha = 1.0f / (1.0f + __expf(-sp_gate_p[0]));
        const int rbase = m * 16;
        f16x8 a_na  = *reinterpret_cast<const f16x8*>(&s_na_h[rbase + arow][kg * 8]);
        f16x8 a_ctx = *reinterpret_cast<const f16x8*>(&s_ctx_h[rbase + arow][kg * 8]);
        float mnr[4], mer[4], vrr[4];
        #pragma unroll
        for (int r = 0; r < 4; ++r) {
            float4 fb4 = s_fb4[rbase + kg * 4 + r];
            mnr[r] = fb4.x; mer[r] = fb4.y; vrr[r] = fb4.z;
        }
        #pragma unroll
        for (int tt = 0; tt < 2; ++tt) {
            const int ct = cq + tt * 4;              // 0..7
            const int col = ct * 16 + arow;          // 0..127
            f16x8 bN = *reinterpret_cast<const f16x8*>(Wn + ((ct * 64) + wl) * 8);
            f16x8 bS = *reinterpret_cast<const f16x8*>(Ws + ((ct * 64) + wl) * 8);
            f32x4 accN = __builtin_amdgcn_mfma_f32_16x16x32_f16(a_na,  bN, f32x4{0.f,0.f,0.f,0.f}, 0,0,0);
            f32x4 accS = __builtin_amdgcn_mfma_f32_16x16x32_f16(a_ctx, bS, f32x4{0.f,0.f,0.f,0.f}, 0,0,0);
            const float nb = non_b[col], sb = spatial_b[col];
            const float w0 = spfb_W[col*3], w1 = spfb_W[col*3+1], w2 = spfb_W[col*3+2];
            const float fbb = spfb_b[col];
            #pragma unroll
            for (int r = 0; r < 4; ++r) {
                const int row = rbase + kg * 4 + r;
                float ne = fmaxf(accN[r] + nb, 0.0f);
                float sa = fmaxf(accS[r] + sb, 0.0f);
                float fb = fmaxf(fbb + w0*mnr[r] + w1*mer[r] + w2*vrr[r], 0.0f);
                float sp = alpha * sa + (1.0f - alpha) * fb;
                float nen = dppmv<QXOR1>(ne);
                float spn = dppmv<QXOR1>(sp);
                if ((arow & 1) == 0) {
                    *reinterpret_cast<unsigned int*>(&s_x[row][col])       = h2u(pkrtz(ne, nen));
                    *reinterpret_cast<unsigned int*>(&s_x[row][128 + col]) = h2u(pkrtz(sp, spn));
                }
            }
        }
    }
    __syncthreads();   // BARRIER 2

    // ================= phase C: fuse GEMM (MFMA f16) + LN partials ==========
    float v[4][4];
    {
        f32x4 acc[4];
        #pragma unroll
        for (int i = 0; i < 4; ++i) acc[i] = f32x4{0.f, 0.f, 0.f, 0.f};
        #pragma unroll
        for (int ks = 0; ks < 8; ++ks) {
            f16x8 a = *reinterpret_cast<const f16x8*>(&s_x[m * 16 + arow][ks * 32 + kg * 8]);
            #pragma unroll
            for (int i = 0; i < 4; ++i) {
                const int ct = cq * 4 + i;           // 0..15
                f16x8 b = *reinterpret_cast<const f16x8*>(Wf + (((ks * 16 + ct) * 64) + wl) * 8);
                acc[i] = __builtin_amdgcn_mfma_f32_16x16x32_f16(a, b, acc[i], 0, 0, 0);
            }
        }
        float psum[4] = {0.f, 0.f, 0.f, 0.f};
        float psq[4]  = {0.f, 0.f, 0.f, 0.f};
        #pragma unroll
        for (int i = 0; i < 4; ++i) {
            const int col = (cq * 4 + i) * 16 + arow;
            const float bias = fuse_b[col];
            #pragma unroll
            for (int r = 0; r < 4; ++r) {
                float x = fmaxf(acc[i][r] + bias, 0.0f);
                v[i][r] = x;
                psum[r] += x;
                psq[r]  += x * x;
            }
        }
        #pragma unroll
        for (int r = 0; r < 4; ++r) {
            psum[r] = sum16(psum[r]);
            psq[r]  = sum16(psq[r]);
        }
        if (arow == 0) {
            #pragma unroll
            for (int r = 0; r < 4; ++r)
                s_part[m * 16 + kg * 4 + r][cq] = make_float2(psum[r], psq[r]);
        }
    }
    __syncthreads();   // BARRIER 3

    // ================= phase C2: per-row LN stats (32 threads) ==============
    if (t < NROWS) {
        const float4* pp = reinterpret_cast<const float4*>(&s_part[t][0]);
        float4 pa = pp[0], pb = pp[1];
        float sum = pa.x + pa.z + pb.x + pb.z;
        float sq  = pa.y + pa.w + pb.y + pb.w;
        float mean = sum * (1.0f/256.0f);
        float var  = sq * (1.0f/256.0f) - mean * mean;
        float rstd = rsqrtf(var + 1e-5f);
        s_mr[t] = make_float2(mean, rstd);
    }
    __syncthreads();   // BARRIER 4

    // ================= phase D: LN + store ==================================
    {
        float lwv[4], lbv[4];
        #pragma unroll
        for (int i = 0; i < 4; ++i) {
            const int col = (cq * 4 + i) * 16 + arow;
            lwv[i] = ln_w[col]; lbv[i] = ln_b[col];
        }
        #pragma unroll
        for (int r = 0; r < 4; ++r) {
            const int row = m * 16 + kg * 4 + r;
            float2 mr = s_mr[row];
            const long obase = (rowbase + row) * EMBD;
            #pragma unroll
            for (int i = 0; i < 4; ++i) {
                const int col = (cq * 4 + i) * 16 + arow;
                out_x[obase + col] = (v[i][r] - mr.x) * mr.y * lwv[i] + lbv[i];
            }
        }
    }
}

extern "C" void kernel_launch(void* const* d_in, const int* in_sizes, int n_in,
                              void* d_out, int out_size, void* d_ws, size_t ws_size,
                              hipStream_t stream) {
    const float* state     = (const float*)d_in[0];
    const float* token_W   = (const float*)d_in[1];
    const float* token_b   = (const float*)d_in[2];
    const float* query_W   = (const float*)d_in[3];
    const float* query_b   = (const float*)d_in[4];
    const float* rbs       = (const float*)d_in[5];
    const float* vbias     = (const float*)d_in[6];
    const float* ivbias    = (const float*)d_in[7];
    const float* att_ln_w  = (const float*)d_in[8];
    const float* att_ln_b  = (const float*)d_in[9];
    const float* non_W     = (const float*)d_in[10];
    const float* non_b     = (const float*)d_in[11];
    const float* spfb_W    = (const float*)d_in[12];
    const float* spfb_b    = (const float*)d_in[13];
    const float* sp_gate   = (const float*)d_in[14];
    const float* spatial_W = (const float*)d_in[15];
    const float* spatial_b = (const float*)d_in[16];
    const float* fuse_W    = (const float*)d_in[17];
    const float* fuse_b    = (const float*)d_in[18];
    const float* ln_w      = (const float*)d_in[19];
    const float* ln_b      = (const float*)d_in[20];

    float* out_x  = (float*)d_out;
    float* out_tf = out_x + (size_t)BH * EMBD;

    unsigned short* wsu = (unsigned short*)d_ws;
    const unsigned short* Wf = wsu;                  // 65536 f16
    const unsigned short* Wn = wsu + 65536;          // 4096 f16
    const unsigned short* Ws = wsu + 65536 + 4096;   // 4096 f16
    const unsigned int* qWh = (const unsigned int*)(wsu + 73728);   // 512
    const unsigned int* TWb = qWh + 512;                            // 128
    const unsigned int* TWp = TWb + 128;                            // 64

    hipLaunchKernelGGL(prep_w_kernel, dim3(39), dim3(256), 0, stream,
                       fuse_W, non_W, spatial_W, query_W, token_W, token_b, wsu);

    hipLaunchKernelGGL(att_state_enc_kernel, dim3(NBLOCKS), dim3(NTHREADS), 0, stream,
        state, query_b, rbs, vbias, ivbias,
        att_ln_w, att_ln_b, non_b, spfb_W, spfb_b, sp_gate, spatial_b,
        Wf, Wn, Ws, qWh, TWb, TWp, fuse_b, ln_w, ln_b, out_x, out_tf);
}